// Round 4
// baseline (923.875 us; speedup 1.0000x reference)
//
#include <hip/hip_runtime.h>
#include <hip/hip_bf16.h>
#include <math.h>

#define N_NODES 190464
#define NPG 186
#define NGRAPH 1024
#define CAP 4096
#define KW 62
#define OCH 8
#define TOUT 125

// ---------- helpers ----------
__device__ __forceinline__ float lrelu2(float v) { return v > 0.f ? v : 0.2f * v; }

// ---------- 1. BN batch statistics ----------
__global__ __launch_bounds__(256) void bn_stats(const float* __restrict__ x,
                                                double* __restrict__ stats) {
    double s[5] = {0, 0, 0, 0, 0}, ss[5] = {0, 0, 0, 0, 0};
    int stride = gridDim.x * blockDim.x;
    for (int n = blockIdx.x * blockDim.x + threadIdx.x; n < N_NODES; n += stride) {
#pragma unroll
        for (int f = 0; f < 5; ++f) {
            float v = x[n * 5 + f];
            s[f] += v;
            ss[f] += (double)v * (double)v;
        }
    }
#pragma unroll
    for (int f = 0; f < 5; ++f) {
        for (int off = 32; off; off >>= 1) {
            s[f] += __shfl_down(s[f], off);
            ss[f] += __shfl_down(ss[f], off);
        }
    }
    if ((threadIdx.x & 63) == 0) {
#pragma unroll
        for (int f = 0; f < 5; ++f) {
            unsafeAtomicAdd(&stats[f], s[f]);
            unsafeAtomicAdd(&stats[5 + f], ss[f]);
        }
    }
}

// ---------- 2. prep: fold BN into lin_w, fold att vectors through wn ----------
// prm layout (floats): wn[480]@0, hb[96]@480, as_w[20]@576, as_b[4]@596,
//                      ad_w[20]@600, ad_b[4]@620   (total 624)
__global__ void prep(const double* __restrict__ stats,
                     const float* __restrict__ gamma,
                     const float* __restrict__ beta,
                     const float* __restrict__ lin_w,
                     const float* __restrict__ att_src,
                     const float* __restrict__ att_dst,
                     float* __restrict__ prm) {
    __shared__ float scale[5], shift[5];
    int t = threadIdx.x;
    if (t < 5) {
        double mu = stats[t] / (double)N_NODES;
        double var = stats[5 + t] / (double)N_NODES - mu * mu;
        double rstd = 1.0 / sqrt(var + 1e-5);
        float sc = (float)rstd * gamma[t];
        scale[t] = sc;
        shift[t] = beta[t] - (float)mu * sc;
    }
    __syncthreads();
    if (t < 96) {
        float hbv = 0.f;
#pragma unroll
        for (int f = 0; f < 5; ++f) {
            float w = lin_w[t * 5 + f];
            prm[t * 5 + f] = w * scale[f];
            hbv += w * shift[f];
        }
        prm[480 + t] = hbv;
    }
    __syncthreads();
    if (t < 8) {
        int h = t & 3;
        const float* att = (t < 4) ? att_src : att_dst;
        int wb = (t < 4) ? 576 : 600;
        int bb = (t < 4) ? 596 : 620;
        float bsum = 0.f;
        float wsum[5] = {0, 0, 0, 0, 0};
        for (int c = 0; c < 24; ++c) {
            float a = att[h * 24 + c];
            int o = h * 24 + c;
#pragma unroll
            for (int f = 0; f < 5; ++f) wsum[f] += a * prm[o * 5 + f];
            bsum += a * prm[480 + o];
        }
#pragma unroll
        for (int f = 0; f < 5; ++f) prm[wb + h * 5 + f] = wsum[f];
        prm[bb + h] = bsum;
    }
}

// ---------- 3. bucket edges by dst graph; pack src|dloc into 4B ----------
__global__ __launch_bounds__(256) void fill_pairs(const int* __restrict__ ei,
                                                  const int E,
                                                  int* __restrict__ gcnt,
                                                  unsigned* __restrict__ pairbuf) {
    int idx = blockIdx.x * 256 + threadIdx.x;
    if (idx >= E) return;
    int src = ei[idx], dst = ei[E + idx];
    int g = dst / NPG;           // magic-mul division
    int dloc = dst - g * NPG;
    int pos = atomicAdd(&gcnt[g], 1);
    if (pos < CAP) pairbuf[(size_t)g * CAP + pos] = (unsigned)src | ((unsigned)dloc << 18);
}

// ---------- 4. per-graph GAT: LDS counting sort + x-space accumulation ----------
__global__ __launch_bounds__(256) void gat_graph(
    const unsigned* __restrict__ pairbuf, const int* __restrict__ gcnt,
    const float* __restrict__ x, const float* __restrict__ prm,
    const float* __restrict__ gat_bias, float* __restrict__ gout) {
    __shared__ unsigned pair_s[CAP];
    __shared__ unsigned lsrc[CAP];
    __shared__ float xg[NPG * 5];
    __shared__ int deg[188];
    __shared__ int rp[188];
    __shared__ int cur[188];
    __shared__ int ts[256];
    __shared__ float prms[624];
    __shared__ float gb[24];

    int g = blockIdx.x, tid = threadIdx.x;
    int ne = min(gcnt[g], CAP);

    for (int i = tid; i < 624; i += 256) prms[i] = prm[i];
    if (tid < 24) gb[tid] = gat_bias[tid];
    for (int i = tid; i < NPG * 5; i += 256) xg[i] = x[(size_t)g * (NPG * 5) + i];
    if (tid < 188) deg[tid] = 0;
    __syncthreads();

    // stage + histogram
    for (int i = tid; i < ne; i += 256) {
        unsigned e = pairbuf[(size_t)g * CAP + i];
        pair_s[i] = e;
        atomicAdd(&deg[e >> 18], 1);
    }
    __syncthreads();

    // exclusive scan of 186 degrees (Hillis-Steele over 256 threads)
    int v = (tid < NPG) ? deg[tid] : 0;
    ts[tid] = v;
    __syncthreads();
    for (int off = 1; off < 256; off <<= 1) {
        int u = (tid >= off) ? ts[tid - off] : 0;
        __syncthreads();
        ts[tid] += u;
        __syncthreads();
    }
    if (tid < NPG) { rp[tid] = ts[tid] - v; cur[tid] = ts[tid] - v; }
    if (tid == NPG - 1) rp[NPG] = ts[tid];
    __syncthreads();

    // scatter into per-dst runs
    for (int i = tid; i < ne; i += 256) {
        unsigned e = pair_s[i];
        int dl = e >> 18;
        int pos = atomicAdd(&cur[dl], 1);
        lsrc[pos] = e & 0x3FFFFu;
    }
    __syncthreads();

    // compute: quad (4 lanes = 4 heads) per node
    int q = tid >> 2, h = tid & 3;
    const float* asw = &prms[576];
    const float* asb = &prms[596];
    const float* adw = &prms[600];
    const float* adb = &prms[620];
    float aw[5], dw[5];
#pragma unroll
    for (int f = 0; f < 5; ++f) { aw[f] = asw[h * 5 + f]; dw[f] = adw[h * 5 + f]; }
    float ab = asb[h], db = adb[h];

    for (int nl = q; nl < NPG; nl += 64) {
        float xd[5];
#pragma unroll
        for (int f = 0; f < 5; ++f) xd[f] = xg[nl * 5 + f];
        float ad = db, as = ab;
#pragma unroll
        for (int f = 0; f < 5; ++f) { ad += dw[f] * xd[f]; as += aw[f] * xd[f]; }
        // self-loop
        float e = __expf(lrelu2(as + ad));
        float denom = e;
        float ax[5];
#pragma unroll
        for (int f = 0; f < 5; ++f) ax[f] = e * xd[f];
        // in-edges
        int b = rp[nl], en = rp[nl + 1];
        for (int i = b; i < en; ++i) {
            int s = lsrc[i];
            const float* xp = x + (size_t)s * 5;
            float xs[5];
#pragma unroll
            for (int f = 0; f < 5; ++f) xs[f] = xp[f];
            float a2 = ab;
#pragma unroll
            for (int f = 0; f < 5; ++f) a2 += aw[f] * xs[f];
            float ee = __expf(lrelu2(a2 + ad));
            denom += ee;
#pragma unroll
            for (int f = 0; f < 5; ++f) ax[f] += ee * xs[f];
        }
        float inv = 1.f / (denom + 1e-16f);
#pragma unroll
        for (int f = 0; f < 5; ++f) ax[f] *= inv;
        // expand to 24 channels, head-mean via quad shuffle, bias + ELU
        float* go = gout + ((size_t)g * NPG + nl) * 24;
#pragma unroll
        for (int c = 0; c < 24; ++c) {
            int o = h * 24 + c;
            float vv = prms[480 + o];
#pragma unroll
            for (int f = 0; f < 5; ++f) vv += prms[o * 5 + f] * ax[f];
            vv *= 0.25f;
            vv += __shfl_xor(vv, 1);
            vv += __shfl_xor(vv, 2);
            if ((c & 3) == h) {
                vv += gb[c];
                go[c] = vv > 0.f ? vv : expm1f(vv);
            }
        }
    }
}

// ---------- 5. per-graph Conv1d(24->8, k=62) + leaky_relu ----------
__global__ __launch_bounds__(256) void conv_k(
    const float* __restrict__ gat, const float* __restrict__ w,
    const float* __restrict__ b, float* __restrict__ out) {
    __shared__ float it[24][192];
    __shared__ float wsh[OCH * 24 * KW];  // 11904 floats
    int g = blockIdx.x, tid = threadIdx.x;
    for (int i = tid; i < NPG * 24; i += 256) {
        int p = i / 24, c = i % 24;
        it[c][p] = gat[(size_t)g * (NPG * 24) + i];
    }
    if (tid < 24 * 6) {
        int c = tid / 6;
        it[c][186 + (tid % 6)] = 0.f;
    }
    for (int i = tid; i < OCH * 24 * KW; i += 256) wsh[i] = w[i];
    __syncthreads();

    int o = tid >> 5, tt = tid & 31;
    int t0 = tt * 4;
    float bias = b[o];
    float a0 = bias, a1 = bias, a2 = bias, a3 = bias;
    for (int i = 0; i < 24; ++i) {
        const float* wr = &wsh[(o * 24 + i) * KW];
        const float* ir = &it[i][t0];
        float v0 = ir[0], v1 = ir[1], v2 = ir[2];
#pragma unroll
        for (int k = 0; k < KW; ++k) {
            float v3 = ir[k + 3];
            float wv = wr[k];
            a0 += wv * v0;
            a1 += wv * v1;
            a2 += wv * v2;
            a3 += wv * v3;
            v0 = v1; v1 = v2; v2 = v3;
        }
    }
    a0 = a0 > 0.f ? a0 : 0.01f * a0;
    a1 = a1 > 0.f ? a1 : 0.01f * a1;
    a2 = a2 > 0.f ? a2 : 0.01f * a2;
    a3 = a3 > 0.f ? a3 : 0.01f * a3;
    size_t base = ((size_t)g * OCH + o) * TOUT + t0;
    if (t0 + 0 < TOUT) out[base + 0] = a0;
    if (t0 + 1 < TOUT) out[base + 1] = a1;
    if (t0 + 2 < TOUT) out[base + 2] = a2;
    if (t0 + 3 < TOUT) out[base + 3] = a3;
}

extern "C" void kernel_launch(void* const* d_in, const int* in_sizes, int n_in,
                              void* d_out, int out_size, void* d_ws, size_t ws_size,
                              hipStream_t stream) {
    const float* x        = (const float*)d_in[0];
    const int*   ei       = (const int*)d_in[1];
    const float* bn_gamma = (const float*)d_in[3];
    const float* bn_beta  = (const float*)d_in[4];
    const float* lin_w    = (const float*)d_in[5];
    const float* att_src  = (const float*)d_in[6];
    const float* att_dst  = (const float*)d_in[7];
    const float* gat_bias = (const float*)d_in[8];
    const float* conv_w   = (const float*)d_in[9];
    const float* conv_b   = (const float*)d_in[10];
    float* out = (float*)d_out;
    float* wsf = (float*)d_ws;
    int*   wsi = (int*)d_ws;

    const int E = in_sizes[1] / 2;

    // ws layout (4-byte units):
    // [0..64)            stats: double sum[5]+sumsq[5]
    // [64..1088)         gcnt: 1024 ints
    // [1088..1712)       prm: 624 floats
    // [1728..1728+1024*4096)  pairbuf (packed src|dloc<<18)
    // then               gout: N*24 floats
    int*      gcnt    = wsi + 64;
    float*    prm     = wsf + 1088;
    unsigned* pairbuf = (unsigned*)(wsi + 1728);
    float*    gout    = (float*)(pairbuf + (size_t)NGRAPH * CAP);

    // zero stats + gcnt in one contiguous memset (4352 B)
    hipMemsetAsync(d_ws, 0, (64 + NGRAPH) * 4, stream);

    bn_stats<<<256, 256, 0, stream>>>(x, (double*)wsf);
    prep<<<1, 128, 0, stream>>>((const double*)wsf, bn_gamma, bn_beta, lin_w,
                                att_src, att_dst, prm);
    fill_pairs<<<(E + 255) / 256, 256, 0, stream>>>(ei, E, gcnt, pairbuf);
    gat_graph<<<NGRAPH, 256, 0, stream>>>(pairbuf, gcnt, x, prm, gat_bias, gout);
    conv_k<<<NGRAPH, 256, 0, stream>>>(gout, conv_w, conv_b, out);
}

// Round 5
// 372.858 us; speedup vs baseline: 2.4778x; 2.4778x over previous
//
#include <hip/hip_runtime.h>
#include <hip/hip_bf16.h>
#include <math.h>

#define N_NODES 190464
#define NPG 186
#define NGRAPH 1024
#define CAP 4096
#define KW 62
#define OCH 8
#define TOUT 125
#define BCHUNK 4096
#define NBLK 744   // 744 * 4096 == 3047424 == E

// ---------- helpers ----------
__device__ __forceinline__ float lrelu2(float v) { return v > 0.f ? v : 0.2f * v; }

// ---------- 1. BN batch statistics ----------
__global__ __launch_bounds__(256) void bn_stats(const float* __restrict__ x,
                                                double* __restrict__ stats) {
    double s[5] = {0, 0, 0, 0, 0}, ss[5] = {0, 0, 0, 0, 0};
    int stride = gridDim.x * blockDim.x;
    for (int n = blockIdx.x * blockDim.x + threadIdx.x; n < N_NODES; n += stride) {
#pragma unroll
        for (int f = 0; f < 5; ++f) {
            float v = x[n * 5 + f];
            s[f] += v;
            ss[f] += (double)v * (double)v;
        }
    }
#pragma unroll
    for (int f = 0; f < 5; ++f) {
        for (int off = 32; off; off >>= 1) {
            s[f] += __shfl_down(s[f], off);
            ss[f] += __shfl_down(ss[f], off);
        }
    }
    if ((threadIdx.x & 63) == 0) {
#pragma unroll
        for (int f = 0; f < 5; ++f) {
            unsafeAtomicAdd(&stats[f], s[f]);
            unsafeAtomicAdd(&stats[5 + f], ss[f]);
        }
    }
}

// ---------- 2. prep: fold BN into lin_w, fold att vectors through wn ----------
// prm layout (floats): wn[480]@0, hb[96]@480, as_w[20]@576, as_b[4]@596,
//                      ad_w[20]@600, ad_b[4]@620   (total 624)
__global__ void prep(const double* __restrict__ stats,
                     const float* __restrict__ gamma,
                     const float* __restrict__ beta,
                     const float* __restrict__ lin_w,
                     const float* __restrict__ att_src,
                     const float* __restrict__ att_dst,
                     float* __restrict__ prm) {
    __shared__ float scale[5], shift[5];
    int t = threadIdx.x;
    if (t < 5) {
        double mu = stats[t] / (double)N_NODES;
        double var = stats[5 + t] / (double)N_NODES - mu * mu;
        double rstd = 1.0 / sqrt(var + 1e-5);
        float sc = (float)rstd * gamma[t];
        scale[t] = sc;
        shift[t] = beta[t] - (float)mu * sc;
    }
    __syncthreads();
    if (t < 96) {
        float hbv = 0.f;
#pragma unroll
        for (int f = 0; f < 5; ++f) {
            float w = lin_w[t * 5 + f];
            prm[t * 5 + f] = w * scale[f];
            hbv += w * shift[f];
        }
        prm[480 + t] = hbv;
    }
    __syncthreads();
    if (t < 8) {
        int h = t & 3;
        const float* att = (t < 4) ? att_src : att_dst;
        int wb = (t < 4) ? 576 : 600;
        int bb = (t < 4) ? 596 : 620;
        float bsum = 0.f;
        float wsum[5] = {0, 0, 0, 0, 0};
        for (int c = 0; c < 24; ++c) {
            float a = att[h * 24 + c];
            int o = h * 24 + c;
#pragma unroll
            for (int f = 0; f < 5; ++f) wsum[f] += a * prm[o * 5 + f];
            bsum += a * prm[480 + o];
        }
#pragma unroll
        for (int f = 0; f < 5; ++f) prm[wb + h * 5 + f] = wsum[f];
        prm[bb + h] = bsum;
    }
}

// ---------- 3. hierarchical bucket-by-graph: LDS hist -> 1 global atomic ----------
__global__ __launch_bounds__(256) void bucket_pairs(const int* __restrict__ ei,
                                                    const int E,
                                                    int* __restrict__ gcnt,
                                                    unsigned* __restrict__ pairbuf) {
    __shared__ int h[NGRAPH];
    int tid = threadIdx.x;
    int e0 = blockIdx.x * BCHUNK;
#pragma unroll
    for (int i = tid; i < NGRAPH; i += 256) h[i] = 0;
    __syncthreads();
    // pass 1: LDS histogram of dst graphs
    for (int i = tid; i < BCHUNK; i += 256) {
        int dst = ei[E + e0 + i];
        unsigned g = (unsigned)dst / NPG;
        atomicAdd(&h[g], 1);
    }
    __syncthreads();
    // reserve contiguous slots per graph with ONE global atomic each
    for (int g = tid; g < NGRAPH; g += 256) {
        int c = h[g];
        h[g] = c ? atomicAdd(&gcnt[g], c) : 0;   // h[g] becomes cursor base
    }
    __syncthreads();
    // pass 2: scatter with LDS cursors (L2-hot re-read)
    for (int i = tid; i < BCHUNK; i += 256) {
        int src = ei[e0 + i];
        int dst = ei[E + e0 + i];
        unsigned g = (unsigned)dst / NPG;
        int dloc = dst - (int)g * NPG;
        int pos = atomicAdd(&h[g], 1);
        if (pos < CAP)
            pairbuf[(size_t)g * CAP + pos] = (unsigned)src | ((unsigned)dloc << 18);
    }
}

// ---------- 4. per-graph GAT: LDS counting sort + x-space accumulation ----------
__global__ __launch_bounds__(256) void gat_graph(
    const unsigned* __restrict__ pairbuf, const int* __restrict__ gcnt,
    const float* __restrict__ x, const float* __restrict__ prm,
    const float* __restrict__ gat_bias, float* __restrict__ gout) {
    __shared__ unsigned pair_s[CAP];
    __shared__ unsigned lsrc[CAP];
    __shared__ float xg[NPG * 5];
    __shared__ int deg[188];
    __shared__ int rp[188];
    __shared__ int cur[188];
    __shared__ int ts[256];
    __shared__ float prms[624];
    __shared__ float gb[24];

    int g = blockIdx.x, tid = threadIdx.x;
    int ne = min(gcnt[g], CAP);

    for (int i = tid; i < 624; i += 256) prms[i] = prm[i];
    if (tid < 24) gb[tid] = gat_bias[tid];
    for (int i = tid; i < NPG * 5; i += 256) xg[i] = x[(size_t)g * (NPG * 5) + i];
    if (tid < 188) deg[tid] = 0;
    __syncthreads();

    // stage + histogram
    for (int i = tid; i < ne; i += 256) {
        unsigned e = pairbuf[(size_t)g * CAP + i];
        pair_s[i] = e;
        atomicAdd(&deg[e >> 18], 1);
    }
    __syncthreads();

    // exclusive scan of 186 degrees (Hillis-Steele over 256 threads)
    int v = (tid < NPG) ? deg[tid] : 0;
    ts[tid] = v;
    __syncthreads();
    for (int off = 1; off < 256; off <<= 1) {
        int u = (tid >= off) ? ts[tid - off] : 0;
        __syncthreads();
        ts[tid] += u;
        __syncthreads();
    }
    if (tid < NPG) { rp[tid] = ts[tid] - v; cur[tid] = ts[tid] - v; }
    if (tid == NPG - 1) rp[NPG] = ts[tid];
    __syncthreads();

    // scatter into per-dst runs
    for (int i = tid; i < ne; i += 256) {
        unsigned e = pair_s[i];
        int dl = e >> 18;
        int pos = atomicAdd(&cur[dl], 1);
        lsrc[pos] = e & 0x3FFFFu;
    }
    __syncthreads();

    // compute: quad (4 lanes = 4 heads) per node
    int q = tid >> 2, h = tid & 3;
    const float* asw = &prms[576];
    const float* asb = &prms[596];
    const float* adw = &prms[600];
    const float* adb = &prms[620];
    float aw[5], dw[5];
#pragma unroll
    for (int f = 0; f < 5; ++f) { aw[f] = asw[h * 5 + f]; dw[f] = adw[h * 5 + f]; }
    float ab = asb[h], db = adb[h];

    for (int nl = q; nl < NPG; nl += 64) {
        float xd[5];
#pragma unroll
        for (int f = 0; f < 5; ++f) xd[f] = xg[nl * 5 + f];
        float ad = db, as = ab;
#pragma unroll
        for (int f = 0; f < 5; ++f) { ad += dw[f] * xd[f]; as += aw[f] * xd[f]; }
        // self-loop
        float e = __expf(lrelu2(as + ad));
        float denom = e;
        float ax[5];
#pragma unroll
        for (int f = 0; f < 5; ++f) ax[f] = e * xd[f];
        // in-edges
        int b = rp[nl], en = rp[nl + 1];
        for (int i = b; i < en; ++i) {
            int s = lsrc[i];
            const float* xp = x + (size_t)s * 5;
            float xs[5];
#pragma unroll
            for (int f = 0; f < 5; ++f) xs[f] = xp[f];
            float a2 = ab;
#pragma unroll
            for (int f = 0; f < 5; ++f) a2 += aw[f] * xs[f];
            float ee = __expf(lrelu2(a2 + ad));
            denom += ee;
#pragma unroll
            for (int f = 0; f < 5; ++f) ax[f] += ee * xs[f];
        }
        float inv = 1.f / (denom + 1e-16f);
#pragma unroll
        for (int f = 0; f < 5; ++f) ax[f] *= inv;
        // expand to 24 channels, head-mean via quad shuffle, bias + ELU
        float* go = gout + ((size_t)g * NPG + nl) * 24;
#pragma unroll
        for (int c = 0; c < 24; ++c) {
            int o = h * 24 + c;
            float vv = prms[480 + o];
#pragma unroll
            for (int f = 0; f < 5; ++f) vv += prms[o * 5 + f] * ax[f];
            vv *= 0.25f;
            vv += __shfl_xor(vv, 1);
            vv += __shfl_xor(vv, 2);
            if ((c & 3) == h) {
                vv += gb[c];
                go[c] = vv > 0.f ? vv : expm1f(vv);
            }
        }
    }
}

// ---------- 5. per-graph Conv1d(24->8, k=62) + leaky_relu ----------
__global__ __launch_bounds__(256) void conv_k(
    const float* __restrict__ gat, const float* __restrict__ w,
    const float* __restrict__ b, float* __restrict__ out) {
    __shared__ float it[24][192];
    __shared__ float wsh[OCH * 24 * KW];  // 11904 floats
    int g = blockIdx.x, tid = threadIdx.x;
    for (int i = tid; i < NPG * 24; i += 256) {
        int p = i / 24, c = i % 24;
        it[c][p] = gat[(size_t)g * (NPG * 24) + i];
    }
    if (tid < 24 * 6) {
        int c = tid / 6;
        it[c][186 + (tid % 6)] = 0.f;
    }
    for (int i = tid; i < OCH * 24 * KW; i += 256) wsh[i] = w[i];
    __syncthreads();

    int o = tid >> 5, tt = tid & 31;
    int t0 = tt * 4;
    float bias = b[o];
    float a0 = bias, a1 = bias, a2 = bias, a3 = bias;
    for (int i = 0; i < 24; ++i) {
        const float* wr = &wsh[(o * 24 + i) * KW];
        const float* ir = &it[i][t0];
        float v0 = ir[0], v1 = ir[1], v2 = ir[2];
#pragma unroll
        for (int k = 0; k < KW; ++k) {
            float v3 = ir[k + 3];
            float wv = wr[k];
            a0 += wv * v0;
            a1 += wv * v1;
            a2 += wv * v2;
            a3 += wv * v3;
            v0 = v1; v1 = v2; v2 = v3;
        }
    }
    a0 = a0 > 0.f ? a0 : 0.01f * a0;
    a1 = a1 > 0.f ? a1 : 0.01f * a1;
    a2 = a2 > 0.f ? a2 : 0.01f * a2;
    a3 = a3 > 0.f ? a3 : 0.01f * a3;
    size_t base = ((size_t)g * OCH + o) * TOUT + t0;
    if (t0 + 0 < TOUT) out[base + 0] = a0;
    if (t0 + 1 < TOUT) out[base + 1] = a1;
    if (t0 + 2 < TOUT) out[base + 2] = a2;
    if (t0 + 3 < TOUT) out[base + 3] = a3;
}

extern "C" void kernel_launch(void* const* d_in, const int* in_sizes, int n_in,
                              void* d_out, int out_size, void* d_ws, size_t ws_size,
                              hipStream_t stream) {
    const float* x        = (const float*)d_in[0];
    const int*   ei       = (const int*)d_in[1];
    const float* bn_gamma = (const float*)d_in[3];
    const float* bn_beta  = (const float*)d_in[4];
    const float* lin_w    = (const float*)d_in[5];
    const float* att_src  = (const float*)d_in[6];
    const float* att_dst  = (const float*)d_in[7];
    const float* gat_bias = (const float*)d_in[8];
    const float* conv_w   = (const float*)d_in[9];
    const float* conv_b   = (const float*)d_in[10];
    float* out = (float*)d_out;
    float* wsf = (float*)d_ws;
    int*   wsi = (int*)d_ws;

    const int E = in_sizes[1] / 2;

    // ws layout (4-byte units):
    // [0..64)            stats: double sum[5]+sumsq[5]
    // [64..1088)         gcnt: 1024 ints
    // [1088..1712)       prm: 624 floats
    // [1728..1728+1024*4096)  pairbuf (packed src|dloc<<18)
    // then               gout: N*24 floats
    int*      gcnt    = wsi + 64;
    float*    prm     = wsf + 1088;
    unsigned* pairbuf = (unsigned*)(wsi + 1728);
    float*    gout    = (float*)(pairbuf + (size_t)NGRAPH * CAP);

    // zero stats + gcnt in one contiguous memset (4352 B)
    hipMemsetAsync(d_ws, 0, (64 + NGRAPH) * 4, stream);

    bn_stats<<<256, 256, 0, stream>>>(x, (double*)wsf);
    prep<<<1, 128, 0, stream>>>((const double*)wsf, bn_gamma, bn_beta, lin_w,
                                att_src, att_dst, prm);
    bucket_pairs<<<NBLK, 256, 0, stream>>>(ei, E, gcnt, pairbuf);
    gat_graph<<<NGRAPH, 256, 0, stream>>>(pairbuf, gcnt, x, prm, gat_bias, gout);
    conv_k<<<NGRAPH, 256, 0, stream>>>(gout, conv_w, conv_b, out);
}